// Round 14
// baseline (167.310 us; speedup 1.0000x reference)
//
#include <hip/hip_runtime.h>

// out = segment_sum( coef(e_feat) * (emb[src] ⊙ weight), dst, N )
// coef(v) = sw[0] + (v==0)*sw[1] + (v==2)*sw[2] + (v==4)*sw[3] + (v==6)*sw[4]
//
// R13: k_bin (unchanged from R12) -> k_sortgather (fused regroup+gather):
//   block per 128-node bucket: LDS-sort records by node, then 8 waves gather
//   16 nodes each, records read via uniform LDS broadcast, 8 accumulators,
//   one coalesced row store. recs2/meta round-trip eliminated.

#define DIM 64
#define LOGB 7
#define NPB 128                 // nodes per bucket
#define NBUK_MAX 1024
#define CAP 2048                // record slots per bucket (avg load ~1280)
#define CHUNK 4096              // edges per bin block
#define OVF_CAP 8192

// ---------------- pass A: LDS-staged binning (byte-identical to R12) ----------------
__global__ __launch_bounds__(512) void k_bin(
    const int* __restrict__ e_feat, const int* __restrict__ src_idx,
    const int* __restrict__ dst_idx,
    int* __restrict__ cursor, int* __restrict__ ovf_cnt, int4* __restrict__ ovf,
    unsigned int* __restrict__ recs, int E, int nbuk)
{
    __shared__ int hist[NBUK_MAX];
    __shared__ int start[NBUK_MAX];
    __shared__ int adjs[NBUK_MAX];
    __shared__ int partial[512];
    __shared__ unsigned int stage_rec[CHUNK];
    __shared__ unsigned short stage_b[CHUNK];

    const int t = threadIdx.x;
    const int base = blockIdx.x * CHUNK;
    int n = E - base; if (n > CHUNK) n = CHUNK;

    hist[t] = 0; hist[t + 512] = 0;
    __syncthreads();

    unsigned int rec[8]; int bk[8]; int lr[8];
    #pragma unroll
    for (int k = 0; k < 8; ++k) {
        int i = t + k * 512;
        if (i < n) {
            int j = base + i;
            int d = dst_idx[j];
            int s = src_idx[j];
            int f = e_feat[j];
            bk[k]  = d >> LOGB;
            rec[k] = (unsigned)s | ((unsigned)(d & (NPB - 1)) << 17)
                                 | ((unsigned)f << 24);
            lr[k]  = atomicAdd(&hist[bk[k]], 1);
        } else bk[k] = -1;
    }
    __syncthreads();

    int a  = hist[2 * t];
    int b2 = hist[2 * t + 1];
    partial[t] = a + b2;
    __syncthreads();
    for (int off = 1; off < 512; off <<= 1) {
        int v = (t >= off) ? partial[t - off] : 0;
        __syncthreads();
        partial[t] += v;
        __syncthreads();
    }
    int pbase = partial[t] - (a + b2);
    start[2 * t]     = pbase;
    start[2 * t + 1] = pbase + a;
    __syncthreads();

    #pragma unroll
    for (int k = 0; k < 8; ++k) {
        if (bk[k] >= 0) {
            int pos = start[bk[k]] + lr[k];
            stage_rec[pos] = rec[k];
            stage_b[pos]   = (unsigned short)bk[k];
        }
    }
    for (int b = t; b < nbuk; b += 512) {
        int c = hist[b];
        if (c > 0) {
            int g0 = atomicAdd(&cursor[b], c);
            adjs[b] = g0 - start[b];
        }
    }
    __syncthreads();

    for (int i = t; i < n; i += 512) {
        int b  = stage_b[i];
        int dp = adjs[b] + i;
        unsigned int r = stage_rec[i];
        if (dp < CAP) {
            recs[(size_t)b * CAP + dp] = r;
        } else {
            int oi = atomicAdd(ovf_cnt, 1);
            if (oi < OVF_CAP) {
                int s  = r & 0x1FFFF;
                int dl = (r >> 17) & (NPB - 1);
                int f  = (r >> 24) & 7;
                ovf[oi] = make_int4((b << LOGB) | dl, s, f, 0);
            }
        }
    }
}

// ---------------- pass B: fused node-sort + gather ----------------
__global__ __launch_bounds__(512) void k_sortgather(
    const float* __restrict__ emb, const float* __restrict__ weight,
    const float* __restrict__ sw,
    const int* __restrict__ cursor, const unsigned int* __restrict__ recs,
    float* __restrict__ out, int N)
{
    __shared__ int hist2[NPB];
    __shared__ int nstart[NPB];
    __shared__ int sc[NPB];
    __shared__ int2 rbuf[CAP];               // 16 KB

    const int t    = threadIdx.x;
    const int b    = blockIdx.x;
    const int lane = t & 63;
    const int wv   = t >> 6;                 // 0..7

    int cnt = cursor[b]; if (cnt > CAP) cnt = CAP;

    if (t < NPB) hist2[t] = 0;
    __syncthreads();

    float s0 = sw[0], s1 = sw[1], s2 = sw[2], s3 = sw[3], s4 = sw[4];

    // ---- sort phase (R12 regroup logic, 512 thr, 4 recs/thread) ----
    unsigned int r[4]; int nl[4]; int lr[4];
    #pragma unroll
    for (int k = 0; k < 4; ++k) {
        int i = t + k * 512;
        if (i < cnt) {
            r[k]  = recs[(size_t)b * CAP + i];
            nl[k] = (r[k] >> 17) & (NPB - 1);
            lr[k] = atomicAdd(&hist2[nl[k]], 1);
        } else nl[k] = -1;
    }
    __syncthreads();

    // exclusive scan of hist2[0..128)
    if (t < NPB) sc[t] = hist2[t];
    __syncthreads();
    for (int off = 1; off < NPB; off <<= 1) {
        int v = (t < NPB && t >= off) ? sc[t - off] : 0;
        __syncthreads();
        if (t < NPB) sc[t] += v;
        __syncthreads();
    }
    if (t < NPB) nstart[t] = sc[t] - hist2[t];
    __syncthreads();

    #pragma unroll
    for (int k = 0; k < 4; ++k) {
        if (nl[k] >= 0) {
            int f = (r[k] >> 24) & 7;
            float c = s0;
            c += (f == 0) ? s1 : 0.0f;
            c += (f == 2) ? s2 : 0.0f;
            c += (f == 4) ? s3 : 0.0f;
            c += (f == 6) ? s4 : 0.0f;
            rbuf[nstart[nl[k]] + lr[k]] = make_int2((int)(r[k] & 0x1FFFF),
                                                    __float_as_int(c));
        }
    }
    __syncthreads();

    // ---- gather phase: wave wv handles nodes wv, wv+8, ... ----
    const float wl = weight[lane];
    const int node0 = b << LOGB;

    for (int row = wv; row < NPB; row += 8) {
        int node = node0 + row;
        if (node >= N) break;
        int st = nstart[row];
        int nc = hist2[row];

        float a0=0.f,a1=0.f,a2=0.f,a3=0.f,a4=0.f,a5=0.f,a6=0.f,a7=0.f;
        int j = 0;
        for (; j + 7 < nc; j += 8) {
            // uniform LDS reads -> broadcast, no bank conflicts
            int2 r0 = rbuf[st+j  ], r1 = rbuf[st+j+1];
            int2 r2 = rbuf[st+j+2], r3 = rbuf[st+j+3];
            int2 r4 = rbuf[st+j+4], r5 = rbuf[st+j+5];
            int2 r6 = rbuf[st+j+6], r7 = rbuf[st+j+7];
            a0 = fmaf(__int_as_float(r0.y), emb[(size_t)r0.x * DIM + lane], a0);
            a1 = fmaf(__int_as_float(r1.y), emb[(size_t)r1.x * DIM + lane], a1);
            a2 = fmaf(__int_as_float(r2.y), emb[(size_t)r2.x * DIM + lane], a2);
            a3 = fmaf(__int_as_float(r3.y), emb[(size_t)r3.x * DIM + lane], a3);
            a4 = fmaf(__int_as_float(r4.y), emb[(size_t)r4.x * DIM + lane], a4);
            a5 = fmaf(__int_as_float(r5.y), emb[(size_t)r5.x * DIM + lane], a5);
            a6 = fmaf(__int_as_float(r6.y), emb[(size_t)r6.x * DIM + lane], a6);
            a7 = fmaf(__int_as_float(r7.y), emb[(size_t)r7.x * DIM + lane], a7);
        }
        for (; j < nc; ++j) {
            int2 rj = rbuf[st + j];
            a0 = fmaf(__int_as_float(rj.y), emb[(size_t)rj.x * DIM + lane], a0);
        }
        float acc = ((a0 + a1) + (a2 + a3)) + ((a4 + a5) + (a6 + a7));
        out[(size_t)node * DIM + lane] = acc * wl;
    }
}

// ---------------- pass C: overflow fixup (normally zero work) ----------------
__global__ __launch_bounds__(64) void k_overflow(
    const int* __restrict__ ovf_cnt, const int4* __restrict__ ovf,
    const float* __restrict__ emb, const float* __restrict__ weight,
    const float* __restrict__ sw, float* __restrict__ out)
{
    int m = *ovf_cnt; if (m > OVF_CAP) m = OVF_CAP;
    int lane = threadIdx.x;
    float s0 = sw[0], s1 = sw[1], s2 = sw[2], s3 = sw[3], s4 = sw[4];
    for (int i = blockIdx.x; i < m; i += gridDim.x) {
        int4 rec = ovf[i];
        int f = rec.z;
        float c = s0;
        c += (f == 0) ? s1 : 0.0f;
        c += (f == 2) ? s2 : 0.0f;
        c += (f == 4) ? s3 : 0.0f;
        c += (f == 6) ? s4 : 0.0f;
        float v = emb[(size_t)rec.y * DIM + lane] * weight[lane] * c;
        atomicAdd(&out[(size_t)rec.x * DIM + lane], v);
    }
}

// ---------------- fallback (tiny ws): round-1 atomic kernel ----------------
__global__ __launch_bounds__(256) void edge_scatter_kernel(
    const float* __restrict__ emb, const int* __restrict__ e_feat,
    const int* __restrict__ src_idx, const int* __restrict__ dst_idx,
    const float* __restrict__ weight, const float* __restrict__ sw,
    float* __restrict__ out, int n_edges) {
    int tid = blockIdx.x * blockDim.x + threadIdx.x;
    int edge = tid >> 4;
    int quad = tid & 15;
    if (edge >= n_edges) return;
    int ef = e_feat[edge];
    float coef = sw[0];
    coef += (ef == 0) ? sw[1] : 0.0f;
    coef += (ef == 2) ? sw[2] : 0.0f;
    coef += (ef == 4) ? sw[3] : 0.0f;
    coef += (ef == 6) ? sw[4] : 0.0f;
    int src = src_idx[edge], dst = dst_idx[edge];
    const float4 ev = *reinterpret_cast<const float4*>(emb + (size_t)src * DIM + quad * 4);
    const float4 wv = *reinterpret_cast<const float4*>(weight + quad * 4);
    float* op = out + (size_t)dst * DIM + quad * 4;
    atomicAdd(op + 0, ev.x * wv.x * coef);
    atomicAdd(op + 1, ev.y * wv.y * coef);
    atomicAdd(op + 2, ev.z * wv.z * coef);
    atomicAdd(op + 3, ev.w * wv.w * coef);
}

extern "C" void kernel_launch(void* const* d_in, const int* in_sizes, int n_in,
                              void* d_out, int out_size, void* d_ws, size_t ws_size,
                              hipStream_t stream) {
    const float* emb     = (const float*)d_in[0];
    const int*   e_feat  = (const int*)d_in[1];
    const int*   src_idx = (const int*)d_in[2];
    const int*   dst_idx = (const int*)d_in[3];
    const float* weight  = (const float*)d_in[4];
    const float* sw      = (const float*)d_in[5];
    float* out = (float*)d_out;

    const int E = in_sizes[1];
    const int N = in_sizes[0] / DIM;
    const int nbuk = (N + NPB - 1) / NPB;    // 782 for N=100000

    // ws: cursor[nbuk] | ovf_cnt | ovf[OVF_CAP] | recs[nbuk*CAP] u32
    size_t off_cursor = 0;
    size_t off_ovfcnt = off_cursor + (size_t)nbuk * 4;
    size_t off_ovf    = (off_ovfcnt + 4 + 15) & ~(size_t)15;
    size_t off_recs   = (off_ovf + (size_t)OVF_CAP * 16 + 15) & ~(size_t)15;
    size_t needed     = off_recs + (size_t)nbuk * CAP * 4;

    if (nbuk > NBUK_MAX || ws_size < needed) {
        hipMemsetAsync(d_out, 0, (size_t)out_size * sizeof(float), stream);
        int total = E * 16, block = 256;
        edge_scatter_kernel<<<(total + block - 1) / block, block, 0, stream>>>(
            emb, e_feat, src_idx, dst_idx, weight, sw, out, E);
        return;
    }

    char* ws = (char*)d_ws;
    int*          cursor  = (int*)(ws + off_cursor);
    int*          ovf_cnt = (int*)(ws + off_ovfcnt);
    int4*         ovf     = (int4*)(ws + off_ovf);
    unsigned int* recs    = (unsigned int*)(ws + off_recs);

    hipMemsetAsync(cursor, 0, off_ovfcnt + 16 - off_cursor, stream);

    k_bin<<<(E + CHUNK - 1) / CHUNK, 512, 0, stream>>>(
        e_feat, src_idx, dst_idx, cursor, ovf_cnt, ovf, recs, E, nbuk);

    k_sortgather<<<nbuk, 512, 0, stream>>>(emb, weight, sw, cursor, recs, out, N);

    k_overflow<<<64, 64, 0, stream>>>(ovf_cnt, ovf, emb, weight, sw, out);
}